// Round 3
// baseline (88.903 us; speedup 1.0000x reference)
//
#include <hip/hip_runtime.h>

// DirectMaskedProjection: H=W=128, D=64, HIDDEN=64, mask vol 128^3 fp32 (binary).
// Round 3: (a) 4 x 16B row loads (imm offsets 0/16/2048/2064 off one per-lane
// address) instead of 8 scattered word loads; (b) boolean mask via OR of
// conditioned 128-bit rows (exact: m!=0 <=> some corner valid&bit&wgt!=0,
// all weights >= 0, binary volume); (c) float2 (v_pk_fma_f32) MLP;
// (d) wave-uniform skips for fully-outside / fully-masked columns.
//
// Inputs (fp32): [0] transform [1,4,4], [1] mask_vol [128^3],
//                [2] W1 [3,64], [3] b1 [64], [4] W2 [64,1], [5] b2 [1]
// Output: fp32 [1,128,128] = 16384 elements.

#define NH 128
#define NW 128
#define ND 64
#define HID 64
#define BITS_PAD 4096   // byte offset of packed bits inside d_ws (row-load slack)

typedef unsigned long long u64;
typedef unsigned int u32;

// Pack vol!=0 into bits: voxel t -> bit (t&63) of u64 word (t>>6); x fastest.
// One row (z,y) = 128 bits = 16 B at byte offset (z*128+y)*16.
__global__ __launch_bounds__(256) void pack_kernel(
    const float* __restrict__ vol,
    u64* __restrict__ bits)
{
    const int t = blockIdx.x * 256 + threadIdx.x;   // 2^21 voxels
    const float v = vol[t];
    const u64 b = __ballot(v != 0.0f);
    if ((threadIdx.x & 63) == 0)
        bits[t >> 6] = b;
}

__global__ __launch_bounds__(256) void dmp_kernel(
    const float* __restrict__ T,          // [16]
    const char* __restrict__ ws,          // d_ws; packed bits at ws+BITS_PAD
    const float* __restrict__ W1,         // [3,64] row-major
    const float* __restrict__ b1,         // [64]
    const float* __restrict__ W2,         // [64]
    const float* __restrict__ b2,         // [1]
    float* __restrict__ out)              // [128*128]
{
    const int t   = blockIdx.x * 256 + threadIdx.x;   // point index
    const int d   = t & 63;                           // depth sample == lane
    const int pix = t >> 6;                           // pixel index h*128+w
    const int h   = pix >> 7;
    const int w   = pix & 127;

    // centered base grid: x=h-63.5, y=w-63.5, z=(d-31.5)*2
    const float bx = (float)h - 63.5f;
    const float by = (float)w - 63.5f;
    const float bz = ((float)d - 31.5f) * 2.0f;

    // q = T @ [bx,by,bz,1]
    const float q0 = T[0]  * bx + T[1]  * by + T[2]  * bz + T[3];
    const float q1 = T[4]  * bx + T[5]  * by + T[6]  * bz + T[7];
    const float q2 = T[8]  * bx + T[9]  * by + T[10] * bz + T[11];
    const float qw = T[12] * bx + T[13] * by + T[14] * bz + T[15];

    // normalize by max|base coord| = 63.5; voxel coords (align_corners=True)
    const float inv_max = 1.0f / 63.5f;
    const float xf = (q0 * inv_max + 1.0f) * 0.5f * 127.0f;
    const float yf = (q1 * inv_max + 1.0f) * 0.5f * 127.0f;
    const float zf = (q2 * inv_max + 1.0f) * 0.5f * 127.0f;
    const float x0f = floorf(xf), y0f = floorf(yf), z0f = floorf(zf);
    const float fx = xf - x0f, fy = yf - y0f, fz = zf - z0f;

    // Per-axis corner usability: valid (ref float tests) AND weight factor != 0.
    const bool uz0 = (z0f >= 0.0f)  && (z0f <= 127.0f) && ((1.0f - fz) != 0.0f);
    const bool uz1 = (z0f >= -1.0f) && (z0f <= 126.0f) && (fz != 0.0f);
    const bool uy0 = (y0f >= 0.0f)  && (y0f <= 127.0f) && ((1.0f - fy) != 0.0f);
    const bool uy1 = (y0f >= -1.0f) && (y0f <= 126.0f) && (fy != 0.0f);
    const bool ux0 = (x0f >= 0.0f)  && (x0f <= 127.0f) && ((1.0f - fx) != 0.0f);
    const bool ux1 = (x0f >= -1.0f) && (x0f <= 126.0f) && (fx != 0.0f);

    const bool lane_active = (uz0 | uz1) && (uy0 | uy1) && (ux0 | ux1);

    bool mask = false;
    if (__any(lane_active)) {
        // clamped row indices -> one per-lane address; invalid rows read
        // don't-care bytes that stay inside d_ws (BITS_PAD slack both sides).
        const int iz = min(max((int)z0f, -1), 127);
        const int iy = min(max((int)y0f, -1), 127);
        const int off = BITS_PAD + (iz << 11) + (iy << 4);   // >= 2032

        const uint4 r00 = *(const uint4*)(ws + off);          // (z0,y0)
        const uint4 r01 = *(const uint4*)(ws + off + 16);     // (z0,y1)
        const uint4 r10 = *(const uint4*)(ws + off + 2048);   // (z1,y0)
        const uint4 r11 = *(const uint4*)(ws + off + 2064);   // (z1,y1)

        // OR the rows whose (z,y) corner pair is usable into one 128-bit reg
        u64 lo = 0, hi = 0;
        if (uz0 & uy0) { lo |= ((u64)r00.y << 32) | r00.x; hi |= ((u64)r00.w << 32) | r00.z; }
        if (uz0 & uy1) { lo |= ((u64)r01.y << 32) | r01.x; hi |= ((u64)r01.w << 32) | r01.z; }
        if (uz1 & uy0) { lo |= ((u64)r10.y << 32) | r10.x; hi |= ((u64)r10.w << 32) | r10.z; }
        if (uz1 & uy1) { lo |= ((u64)r11.y << 32) | r11.x; hi |= ((u64)r11.w << 32) | r11.z; }

        const int ix0 = (int)x0f;
        const int c0 = min(max(ix0, 0), 127);
        const int c1 = min(max(ix0 + 1, 0), 127);
        const u64 s0 = (c0 & 64) ? hi : lo;
        const u64 s1 = (c1 & 64) ? hi : lo;
        const bool b0 = (s0 >> (c0 & 63)) & 1ull;
        const bool b1 = (s1 >> (c1 & 63)) & 1ull;

        mask = (b0 & ux0) | (b1 & ux1);
    }

    // field MLP: relu(q3 @ W1 + b1) @ W2 + b2, q3 = q/qw (qw == 1).
    float val = 0.0f;
    if (__any(mask)) {
        const float invw = 1.0f / qw;
        const float p0 = q0 * invw, p1 = q1 * invw, p2 = q2 * invw;
        const float2* W1a = (const float2*)W1;          // row 0
        const float2* W1b = (const float2*)(W1 + 64);   // row 1
        const float2* W1c = (const float2*)(W1 + 128);  // row 2
        const float2* B1  = (const float2*)b1;
        const float2* W2v = (const float2*)W2;
        float sx = 0.0f, sy = 0.0f;
        #pragma unroll 8
        for (int j = 0; j < HID / 2; ++j) {
            const float2 wa = W1a[j], wb = W1b[j], wc = W1c[j];
            const float2 bb = B1[j],  w2 = W2v[j];
            float hx = fmaf(p0, wa.x, fmaf(p1, wb.x, fmaf(p2, wc.x, bb.x)));
            float hy = fmaf(p0, wa.y, fmaf(p1, wb.y, fmaf(p2, wc.y, bb.y)));
            hx = fmaxf(hx, 0.0f);
            hy = fmaxf(hy, 0.0f);
            sx = fmaf(hx, w2.x, sx);
            sy = fmaf(hy, w2.y, sy);
        }
        const float pot = sx + sy + b2[0];
        val = mask ? pot : 0.0f;
    }

    // per-pixel reduction over the 64 depth lanes (one full wave)
    #pragma unroll
    for (int off2 = 32; off2 > 0; off2 >>= 1)
        val += __shfl_down(val, off2);

    if (d == 0)
        out[pix] = val * 2.0f;   // * DZ
}

extern "C" void kernel_launch(void* const* d_in, const int* in_sizes, int n_in,
                              void* d_out, int out_size, void* d_ws, size_t ws_size,
                              hipStream_t stream) {
    const float* T   = (const float*)d_in[0];
    const float* vol = (const float*)d_in[1];
    const float* W1  = (const float*)d_in[2];
    const float* b1  = (const float*)d_in[3];
    const float* W2  = (const float*)d_in[4];
    const float* b2  = (const float*)d_in[5];
    float* out = (float*)d_out;

    u64* bits = (u64*)((char*)d_ws + BITS_PAD);   // 256 KB + pad inside d_ws

    // pack 2^21 voxels -> 32768 u64 words
    pack_kernel<<<8192, 256, 0, stream>>>(vol, bits);

    const int n_points = NH * NW * ND;   // 1,048,576
    dmp_kernel<<<n_points / 256, 256, 0, stream>>>(
        T, (const char*)d_ws, W1, b1, W2, b2, out);
}